// Round 1
// baseline (32093.073 us; speedup 1.0000x reference)
//
#include <hip/hip_runtime.h>
#include <hip/hip_bf16.h>

#define B 8
#define S 1024
#define L 1025
#define V 64
#define D 512
#define H 8
#define HD 64
#define NL 6
#define FF 2048
#define MAXD 64
#define OUTLEN 8
#define NC 10

#define BM 64
#define BN 64
#define BK 16

// ---------------- embedding ----------------
__global__ void embed_k(const int* __restrict__ src, const float* __restrict__ emb,
                        const float* __restrict__ cls, float* __restrict__ x)
{
    long i = (long)blockIdx.x * blockDim.x + threadIdx.x; // over B*L*D
    if (i >= (long)B * L * D) return;
    int d = (int)(i % D);
    long bl = i / D;
    int l = (int)(bl % L);
    int b = (int)(bl / L);
    x[i] = (l == 0) ? cls[d] : emb[(long)src[b * S + (l - 1)] * D + d];
}

// ---------------- generic f32 GEMM: C[M,N] = A[M,K] @ W[N,K]^T + bias, opt GELU ----
__global__ __launch_bounds__(256) void gemm_k(const float* __restrict__ A,
                                              const float* __restrict__ W,
                                              const float* __restrict__ bias,
                                              float* __restrict__ C,
                                              int M, int N, int K, int act)
{
    __shared__ float As[BK][BM + 1];
    __shared__ float Bs[BK][BN + 1];
    int tid = threadIdx.x;
    int m0 = blockIdx.y * BM;
    int n0 = blockIdx.x * BN;
    int tx = tid & 15, ty = tid >> 4;
    float acc[4][4] = {};
    for (int k0 = 0; k0 < K; k0 += BK) {
#pragma unroll
        for (int i = 0; i < 4; i++) {
            int idx = tid + i * 256;
            int r = idx >> 4, c = idx & 15;
            int gm = m0 + r;
            As[c][r] = (gm < M) ? A[(long)gm * K + k0 + c] : 0.f;
        }
#pragma unroll
        for (int i = 0; i < 4; i++) {
            int idx = tid + i * 256;
            int r = idx >> 4, c = idx & 15;
            int gn = n0 + r;
            Bs[c][r] = (gn < N) ? W[(long)gn * K + k0 + c] : 0.f;
        }
        __syncthreads();
#pragma unroll
        for (int kk = 0; kk < BK; kk++) {
            float a[4], bv[4];
#pragma unroll
            for (int i = 0; i < 4; i++) a[i] = As[kk][ty * 4 + i];
#pragma unroll
            for (int j = 0; j < 4; j++) bv[j] = Bs[kk][tx * 4 + j];
#pragma unroll
            for (int i = 0; i < 4; i++)
#pragma unroll
                for (int j = 0; j < 4; j++)
                    acc[i][j] += a[i] * bv[j];
        }
        __syncthreads();
    }
#pragma unroll
    for (int i = 0; i < 4; i++) {
        int gm = m0 + ty * 4 + i;
        if (gm >= M) continue;
#pragma unroll
        for (int j = 0; j < 4; j++) {
            int gn = n0 + tx * 4 + j;
            if (gn >= N) continue;
            float v = acc[i][j] + bias[gn];
            if (act == 1) v = 0.5f * v * (1.f + erff(v * 0.70710678118654752f));
            C[(long)gm * N + gn] = v;
        }
    }
}

// ---------------- attention: one block per (q, h, b) ----------------
__global__ __launch_bounds__(256) void attn_k(const float* __restrict__ qkv,
                                              const float* __restrict__ rel_emb_l,
                                              const unsigned char* __restrict__ pad,
                                              float* __restrict__ o)
{
    int q = blockIdx.x;
    int h = blockIdx.y;
    int b = blockIdx.z;
    __shared__ float qs[HD];
    __shared__ float sc[L];
    __shared__ float red[8];
    __shared__ float part[4][HD];
    int tid = threadIdx.x;
    const float scale = 0.125f; // 1/sqrt(HD)
    const float* qptr = qkv + (long)(b * L + q) * (3 * D) + h * HD;
    if (tid < HD) qs[tid] = qptr[tid] * scale;
    __syncthreads();
    // scores
    for (int k = tid; k < L; k += 256) {
        const float* kptr = qkv + (long)(b * L + k) * (3 * D) + D + h * HD;
        const float4* k4 = reinterpret_cast<const float4*>(kptr);
        float s = 0.f;
#pragma unroll
        for (int d4 = 0; d4 < HD / 4; d4++) {
            float4 kv = k4[d4];
            s += qs[d4 * 4 + 0] * kv.x + qs[d4 * 4 + 1] * kv.y +
                 qs[d4 * 4 + 2] * kv.z + qs[d4 * 4 + 3] * kv.w;
        }
        int rel = k - q;
        rel = min(MAXD, max(-MAXD, rel)) + MAXD;
        s += rel_emb_l[rel * H + h];
        bool masked = (k > 0) && (pad[b * S + (k - 1)] != 0);
        sc[k] = masked ? -1e9f : s;
    }
    __syncthreads();
    // max
    float m = -1e30f;
    for (int k = tid; k < L; k += 256) m = fmaxf(m, sc[k]);
    for (int off = 32; off; off >>= 1) m = fmaxf(m, __shfl_down(m, off, 64));
    int lane = tid & 63, wid = tid >> 6;
    if (lane == 0) red[wid] = m;
    __syncthreads();
    if (tid == 0) {
        float mm = red[0];
        for (int i = 1; i < 4; i++) mm = fmaxf(mm, red[i]);
        red[0] = mm;
    }
    __syncthreads();
    m = red[0];
    // exp + sum
    float sum = 0.f;
    for (int k = tid; k < L; k += 256) {
        float e = __expf(sc[k] - m);
        sc[k] = e;
        sum += e;
    }
    for (int off = 32; off; off >>= 1) sum += __shfl_down(sum, off, 64);
    if (lane == 0) red[4 + wid] = sum;
    __syncthreads();
    if (tid == 0) red[4] = 1.f / (red[4] + red[5] + red[6] + red[7]);
    __syncthreads();
    float inv = red[4];
    // output: 4 groups x 64 lanes
    int g = tid >> 6;
    int d = tid & 63;
    float acc = 0.f;
    for (int k = g; k < L; k += 4)
        acc += sc[k] * qkv[(long)(b * L + k) * (3 * D) + 2 * D + h * HD + d];
    part[g][d] = acc;
    __syncthreads();
    if (tid < HD) {
        float r = (part[0][tid] + part[1][tid] + part[2][tid] + part[3][tid]) * inv;
        o[(long)(b * L + q) * D + h * HD + tid] = r;
    }
}

// ---------------- out = LayerNorm(xin + rin) * g + b  (one block per row) ------
__global__ __launch_bounds__(256) void add_ln_k(const float* __restrict__ xin,
                                                const float* __restrict__ rin,
                                                const float* __restrict__ g,
                                                const float* __restrict__ bb,
                                                float* __restrict__ out)
{
    int row = blockIdx.x;
    __shared__ float red[8];
    int tid = threadIdx.x;
    const float* xp = xin + (long)row * D;
    const float* rp = rin + (long)row * D;
    float v0 = xp[tid] + rp[tid];
    float v1 = xp[tid + 256] + rp[tid + 256];
    float s = v0 + v1;
    for (int off = 32; off; off >>= 1) s += __shfl_down(s, off, 64);
    int lane = tid & 63, wid = tid >> 6;
    if (lane == 0) red[wid] = s;
    __syncthreads();
    if (tid == 0) red[0] = red[0] + red[1] + red[2] + red[3];
    __syncthreads();
    float mean = red[0] * (1.f / D);
    float d0 = v0 - mean, d1 = v1 - mean;
    float sq = d0 * d0 + d1 * d1;
    for (int off = 32; off; off >>= 1) sq += __shfl_down(sq, off, 64);
    if (lane == 0) red[4 + wid] = sq;
    __syncthreads();
    if (tid == 0) red[4] = red[4] + red[5] + red[6] + red[7];
    __syncthreads();
    float rs = rsqrtf(red[4] * (1.f / D) + 1e-5f);
    out[(long)row * D + tid] = d0 * rs * g[tid] + bb[tid];
    out[(long)row * D + tid + 256] = d1 * rs * g[tid + 256] + bb[tid + 256];
}

// ---------------- final LN (row 0 only) + classifier ----------------
__global__ __launch_bounds__(256) void cls_k(const float* __restrict__ x,
                                             const float* __restrict__ ng,
                                             const float* __restrict__ nb,
                                             const float* __restrict__ cw,
                                             const float* __restrict__ cb,
                                             float* __restrict__ out)
{
    int b = blockIdx.x;
    __shared__ float xn[D];
    __shared__ float red[8];
    int tid = threadIdx.x;
    const float* xp = x + (long)(b * L) * D; // row 0 of batch b
    float v0 = xp[tid], v1 = xp[tid + 256];
    float s = v0 + v1;
    for (int off = 32; off; off >>= 1) s += __shfl_down(s, off, 64);
    int lane = tid & 63, wid = tid >> 6;
    if (lane == 0) red[wid] = s;
    __syncthreads();
    if (tid == 0) red[0] = red[0] + red[1] + red[2] + red[3];
    __syncthreads();
    float mean = red[0] * (1.f / D);
    float d0 = v0 - mean, d1 = v1 - mean;
    float sq = d0 * d0 + d1 * d1;
    for (int off = 32; off; off >>= 1) sq += __shfl_down(sq, off, 64);
    if (lane == 0) red[4 + wid] = sq;
    __syncthreads();
    if (tid == 0) red[4] = red[4] + red[5] + red[6] + red[7];
    __syncthreads();
    float rs = rsqrtf(red[4] * (1.f / D) + 1e-5f);
    xn[tid] = d0 * rs * ng[tid] + nb[tid];
    xn[tid + 256] = d1 * rs * ng[tid + 256] + nb[tid + 256];
    __syncthreads();
    for (int o = tid; o < OUTLEN * NC; o += 256) {
        float acc = cb[o];
        const float* wp = cw + (long)o * D;
        for (int d = 0; d < D; d++) acc += xn[d] * wp[d];
        out[b * OUTLEN * NC + o] = acc;
    }
}

extern "C" void kernel_launch(void* const* d_in, const int* in_sizes, int n_in,
                              void* d_out, int out_size, void* d_ws, size_t ws_size,
                              hipStream_t stream) {
    const int* src = (const int*)d_in[0];
    const unsigned char* pad = (const unsigned char*)d_in[1];
    const float* emb = (const float*)d_in[2];
    const float* cls_token = (const float*)d_in[3];
    const float* qkv_w = (const float*)d_in[4];
    const float* qkv_b = (const float*)d_in[5];
    const float* out_w = (const float*)d_in[6];
    const float* out_b = (const float*)d_in[7];
    const float* rel_emb = (const float*)d_in[8];
    const float* ln1_g = (const float*)d_in[9];
    const float* ln1_b = (const float*)d_in[10];
    const float* w1 = (const float*)d_in[11];
    const float* b1 = (const float*)d_in[12];
    const float* w2 = (const float*)d_in[13];
    const float* b2 = (const float*)d_in[14];
    const float* ln2_g = (const float*)d_in[15];
    const float* ln2_b = (const float*)d_in[16];
    const float* norm_g = (const float*)d_in[17];
    const float* norm_b = (const float*)d_in[18];
    const float* cls_w = (const float*)d_in[19];
    const float* cls_b = (const float*)d_in[20];
    float* out = (float*)d_out;

    char* ws = (char*)d_ws;
    const size_t XB = (size_t)B * L * D * 4;       // 16.8 MB
    const size_t QB = (size_t)B * L * 3 * D * 4;   // 50.4 MB
    float* x   = (float*)(ws);
    float* qkv = (float*)(ws + XB);
    float* o   = (float*)(ws + XB + QB);
    float* h   = qkv; // reuse [qkv|o] region: exactly B*L*FF*4 bytes
    float* p   = (float*)(ws + XB + QB + XB);      // o_proj / ff buffer
    float* x2  = (float*)(ws + XB + QB + XB + XB);

    const int M = B * L;
    {
        long total = (long)B * L * D;
        embed_k<<<dim3((unsigned)((total + 255) / 256)), 256, 0, stream>>>(src, emb, cls_token, x);
    }
    for (int l = 0; l < NL; l++) {
        const float* qw = qkv_w + (size_t)l * 3 * D * D;
        const float* qb = qkv_b + (size_t)l * 3 * D;
        const float* ow = out_w + (size_t)l * D * D;
        const float* ob = out_b + (size_t)l * D;
        const float* re = rel_emb + (size_t)l * (2 * MAXD + 1) * H;
        const float* g1 = ln1_g + (size_t)l * D;
        const float* be1 = ln1_b + (size_t)l * D;
        const float* W1p = w1 + (size_t)l * FF * D;
        const float* B1p = b1 + (size_t)l * FF;
        const float* W2p = w2 + (size_t)l * D * FF;
        const float* B2p = b2 + (size_t)l * D;
        const float* g2 = ln2_g + (size_t)l * D;
        const float* be2 = ln2_b + (size_t)l * D;

        gemm_k<<<dim3(3 * D / BN, (M + BM - 1) / BM), 256, 0, stream>>>(x, qw, qb, qkv, M, 3 * D, D, 0);
        attn_k<<<dim3(L, H, B), 256, 0, stream>>>(qkv, re, pad, o);
        gemm_k<<<dim3(D / BN, (M + BM - 1) / BM), 256, 0, stream>>>(o, ow, ob, p, M, D, D, 0);
        add_ln_k<<<dim3(M), 256, 0, stream>>>(x, p, g1, be1, x2);
        gemm_k<<<dim3(FF / BN, (M + BM - 1) / BM), 256, 0, stream>>>(x2, W1p, B1p, h, M, FF, D, 1);
        gemm_k<<<dim3(D / BN, (M + BM - 1) / BM), 256, 0, stream>>>(h, W2p, B2p, p, M, D, FF, 0);
        add_ln_k<<<dim3(M), 256, 0, stream>>>(x2, p, g2, be2, x);
    }
    cls_k<<<dim3(B), 256, 0, stream>>>(x, norm_g, norm_b, cls_w, cls_b, out);
}

// Round 2
// 10177.291 us; speedup vs baseline: 3.1534x; 3.1534x over previous
//
#include <hip/hip_runtime.h>
#include <hip/hip_bf16.h>

#define B 8
#define S 1024
#define L 1025
#define V 64
#define D 512
#define H 8
#define HD 64
#define NL 6
#define FF 2048
#define MAXD 64
#define OUTLEN 8
#define NC 10

#define BM 64
#define BN 64
#define BK 16

// ---------------- embedding ----------------
__global__ void embed_k(const int* __restrict__ src, const float* __restrict__ emb,
                        const float* __restrict__ cls, float* __restrict__ x)
{
    long i = (long)blockIdx.x * blockDim.x + threadIdx.x; // over B*L*D
    if (i >= (long)B * L * D) return;
    int d = (int)(i % D);
    long bl = i / D;
    int l = (int)(bl % L);
    int b = (int)(bl / L);
    x[i] = (l == 0) ? cls[d] : emb[(long)src[b * S + (l - 1)] * D + d];
}

// ---------------- generic f32 GEMM: C[M,N] = A[M,K] @ W[N,K]^T + bias, opt GELU ----
__global__ __launch_bounds__(256) void gemm_k(const float* __restrict__ A,
                                              const float* __restrict__ W,
                                              const float* __restrict__ bias,
                                              float* __restrict__ C,
                                              int M, int N, int K, int act)
{
    __shared__ float As[BK][BM + 1];
    __shared__ float Bs[BK][BN + 1];
    int tid = threadIdx.x;
    int m0 = blockIdx.y * BM;
    int n0 = blockIdx.x * BN;
    int tx = tid & 15, ty = tid >> 4;
    float acc[4][4] = {};
    for (int k0 = 0; k0 < K; k0 += BK) {
#pragma unroll
        for (int i = 0; i < 4; i++) {
            int idx = tid + i * 256;
            int r = idx >> 4, c = idx & 15;
            int gm = m0 + r;
            As[c][r] = (gm < M) ? A[(long)gm * K + k0 + c] : 0.f;
        }
#pragma unroll
        for (int i = 0; i < 4; i++) {
            int idx = tid + i * 256;
            int r = idx >> 4, c = idx & 15;
            int gn = n0 + r;
            Bs[c][r] = (gn < N) ? W[(long)gn * K + k0 + c] : 0.f;
        }
        __syncthreads();
#pragma unroll
        for (int kk = 0; kk < BK; kk++) {
            float a[4], bv[4];
#pragma unroll
            for (int i = 0; i < 4; i++) a[i] = As[kk][ty * 4 + i];
#pragma unroll
            for (int j = 0; j < 4; j++) bv[j] = Bs[kk][tx * 4 + j];
#pragma unroll
            for (int i = 0; i < 4; i++)
#pragma unroll
                for (int j = 0; j < 4; j++)
                    acc[i][j] += a[i] * bv[j];
        }
        __syncthreads();
    }
#pragma unroll
    for (int i = 0; i < 4; i++) {
        int gm = m0 + ty * 4 + i;
        if (gm >= M) continue;
#pragma unroll
        for (int j = 0; j < 4; j++) {
            int gn = n0 + tx * 4 + j;
            if (gn >= N) continue;
            float v = acc[i][j] + bias[gn];
            if (act == 1) v = 0.5f * v * (1.f + erff(v * 0.70710678118654752f));
            C[(long)gm * N + gn] = v;
        }
    }
}

// ---------------- flash attention: one block per (64-row q-tile, h, b) --------
// QBLK=64, KBLK=64. 256 threads: tx=tid&15 (4 cols each), ty=tid>>4 (4 rows each).
__global__ __launch_bounds__(256) void fattn_k(const float* __restrict__ qkv,
                                               const float* __restrict__ rel_emb_l,
                                               const unsigned char* __restrict__ pad,
                                               float* __restrict__ o)
{
    int qt = blockIdx.x;
    int h = blockIdx.y;
    int b = blockIdx.z;
    int q0 = qt * 64;
    __shared__ float Qs[64][68];   // [d][r], pre-scaled
    __shared__ float Ks[64][68];   // [d][c]
    __shared__ float Vs[64][68];   // [k][d]
    __shared__ float Ps[64][68];   // [k][r]
    __shared__ float bias_s[2 * MAXD + 1];
    __shared__ unsigned char maskf[64];
    int tid = threadIdx.x;
    int tx = tid & 15, ty = tid >> 4;
    const float scale = 0.125f;
    const long bh_base = (long)(b * L) * (3 * D) + h * HD;

    // Q tile -> LDS transposed, scaled
#pragma unroll
    for (int i = 0; i < 4; i++) {
        int idx = tid + i * 256;           // over 1024 float4 slots
        int r = idx >> 4, c4 = idx & 15;
        int gq = q0 + r;
        float4 v = make_float4(0.f, 0.f, 0.f, 0.f);
        if (gq < L) v = *reinterpret_cast<const float4*>(qkv + bh_base + (long)gq * (3 * D) + c4 * 4);
        Qs[c4 * 4 + 0][r] = v.x * scale;
        Qs[c4 * 4 + 1][r] = v.y * scale;
        Qs[c4 * 4 + 2][r] = v.z * scale;
        Qs[c4 * 4 + 3][r] = v.w * scale;
    }
    for (int rel = tid; rel < 2 * MAXD + 1; rel += 256) bias_s[rel] = rel_emb_l[rel * H + h];

    float Oacc[4][4] = {};
    float m_prev[4], l_sum[4];
#pragma unroll
    for (int i = 0; i < 4; i++) { m_prev[i] = -1e30f; l_sum[i] = 0.f; }

    const int NT = (L + 63) / 64; // 17
    for (int kt = 0; kt < NT; kt++) {
        int k0 = kt * 64;
        __syncthreads(); // previous iter's Ks/Vs/Ps readers done
#pragma unroll
        for (int i = 0; i < 4; i++) {
            int idx = tid + i * 256;
            int r = idx >> 4, c4 = idx & 15;
            int gk = k0 + r;
            float4 kv = make_float4(0.f, 0.f, 0.f, 0.f);
            float4 vv = make_float4(0.f, 0.f, 0.f, 0.f);
            if (gk < L) {
                const float* rowp = qkv + bh_base + (long)gk * (3 * D);
                kv = *reinterpret_cast<const float4*>(rowp + D + c4 * 4);
                vv = *reinterpret_cast<const float4*>(rowp + 2 * D + c4 * 4);
            }
            Ks[c4 * 4 + 0][r] = kv.x;
            Ks[c4 * 4 + 1][r] = kv.y;
            Ks[c4 * 4 + 2][r] = kv.z;
            Ks[c4 * 4 + 3][r] = kv.w;
            *reinterpret_cast<float4*>(&Vs[r][c4 * 4]) = vv;
        }
        if (tid < 64) {
            int gk = k0 + tid;
            maskf[tid] = (gk >= L) || (gk > 0 && pad[b * S + gk - 1] != 0);
        }
        __syncthreads();

        // scores S[4][4]
        float Sv[4][4] = {};
#pragma unroll
        for (int d = 0; d < 64; d++) {
            float4 a = *reinterpret_cast<const float4*>(&Qs[d][ty * 4]);
            float4 bb = *reinterpret_cast<const float4*>(&Ks[d][tx * 4]);
            float av[4] = {a.x, a.y, a.z, a.w};
            float bv[4] = {bb.x, bb.y, bb.z, bb.w};
#pragma unroll
            for (int i = 0; i < 4; i++)
#pragma unroll
                for (int j = 0; j < 4; j++)
                    Sv[i][j] += av[i] * bv[j];
        }
        // bias + mask
#pragma unroll
        for (int i = 0; i < 4; i++) {
            int rg = q0 + ty * 4 + i;
#pragma unroll
            for (int j = 0; j < 4; j++) {
                int cg = k0 + tx * 4 + j;
                int rel = cg - rg;
                rel = min(MAXD, max(-MAXD, rel)) + MAXD;
                Sv[i][j] += bias_s[rel];
                if (maskf[tx * 4 + j]) Sv[i][j] = -1e9f;
            }
        }
        // online softmax (per row, replicated across the 16 tx lanes)
        float Pv[4][4];
#pragma unroll
        for (int i = 0; i < 4; i++) {
            float mx = fmaxf(fmaxf(Sv[i][0], Sv[i][1]), fmaxf(Sv[i][2], Sv[i][3]));
#pragma unroll
            for (int mskk = 1; mskk < 16; mskk <<= 1) mx = fmaxf(mx, __shfl_xor(mx, mskk, 16));
            float mnew = fmaxf(m_prev[i], mx);
            float corr = __expf(m_prev[i] - mnew);
            float ssum = 0.f;
#pragma unroll
            for (int j = 0; j < 4; j++) {
                float p = __expf(Sv[i][j] - mnew);
                Pv[i][j] = p;
                ssum += p;
            }
#pragma unroll
            for (int mskk = 1; mskk < 16; mskk <<= 1) ssum += __shfl_xor(ssum, mskk, 16);
            l_sum[i] = l_sum[i] * corr + ssum;
            m_prev[i] = mnew;
#pragma unroll
            for (int j = 0; j < 4; j++) Oacc[i][j] *= corr;
        }
        // P -> LDS transposed [k][r]
#pragma unroll
        for (int i = 0; i < 4; i++)
#pragma unroll
            for (int j = 0; j < 4; j++)
                Ps[tx * 4 + j][ty * 4 + i] = Pv[i][j];
        __syncthreads();
        // O += P @ V
#pragma unroll
        for (int k = 0; k < 64; k++) {
            float4 a = *reinterpret_cast<const float4*>(&Ps[k][ty * 4]);
            float4 bb = *reinterpret_cast<const float4*>(&Vs[k][tx * 4]);
            float av[4] = {a.x, a.y, a.z, a.w};
            float bv[4] = {bb.x, bb.y, bb.z, bb.w};
#pragma unroll
            for (int i = 0; i < 4; i++)
#pragma unroll
                for (int j = 0; j < 4; j++)
                    Oacc[i][j] += av[i] * bv[j];
        }
    }
    // epilogue
#pragma unroll
    for (int i = 0; i < 4; i++) {
        int rg = q0 + ty * 4 + i;
        if (rg >= L) continue;
        float inv = 1.f / l_sum[i];
        float4 r4 = make_float4(Oacc[i][0] * inv, Oacc[i][1] * inv, Oacc[i][2] * inv, Oacc[i][3] * inv);
        *reinterpret_cast<float4*>(o + (long)(b * L + rg) * D + h * HD + tx * 4) = r4;
    }
}

// ---------------- out = LayerNorm(xin + rin) * g + b  (one block per row) ------
__global__ __launch_bounds__(256) void add_ln_k(const float* __restrict__ xin,
                                                const float* __restrict__ rin,
                                                const float* __restrict__ g,
                                                const float* __restrict__ bb,
                                                float* __restrict__ out)
{
    int row = blockIdx.x;
    __shared__ float red[8];
    int tid = threadIdx.x;
    const float* xp = xin + (long)row * D;
    const float* rp = rin + (long)row * D;
    float v0 = xp[tid] + rp[tid];
    float v1 = xp[tid + 256] + rp[tid + 256];
    float s = v0 + v1;
    for (int off = 32; off; off >>= 1) s += __shfl_down(s, off, 64);
    int lane = tid & 63, wid = tid >> 6;
    if (lane == 0) red[wid] = s;
    __syncthreads();
    if (tid == 0) red[0] = red[0] + red[1] + red[2] + red[3];
    __syncthreads();
    float mean = red[0] * (1.f / D);
    float d0 = v0 - mean, d1 = v1 - mean;
    float sq = d0 * d0 + d1 * d1;
    for (int off = 32; off; off >>= 1) sq += __shfl_down(sq, off, 64);
    if (lane == 0) red[4 + wid] = sq;
    __syncthreads();
    if (tid == 0) red[4] = red[4] + red[5] + red[6] + red[7];
    __syncthreads();
    float rs = rsqrtf(red[4] * (1.f / D) + 1e-5f);
    out[(long)row * D + tid] = d0 * rs * g[tid] + bb[tid];
    out[(long)row * D + tid + 256] = d1 * rs * g[tid + 256] + bb[tid + 256];
}

// ---------------- final LN (row 0 only) + classifier ----------------
__global__ __launch_bounds__(256) void cls_k(const float* __restrict__ x,
                                             const float* __restrict__ ng,
                                             const float* __restrict__ nb,
                                             const float* __restrict__ cw,
                                             const float* __restrict__ cb,
                                             float* __restrict__ out)
{
    int b = blockIdx.x;
    __shared__ float xn[D];
    __shared__ float red[8];
    int tid = threadIdx.x;
    const float* xp = x + (long)(b * L) * D; // row 0 of batch b
    float v0 = xp[tid], v1 = xp[tid + 256];
    float s = v0 + v1;
    for (int off = 32; off; off >>= 1) s += __shfl_down(s, off, 64);
    int lane = tid & 63, wid = tid >> 6;
    if (lane == 0) red[wid] = s;
    __syncthreads();
    if (tid == 0) red[0] = red[0] + red[1] + red[2] + red[3];
    __syncthreads();
    float mean = red[0] * (1.f / D);
    float d0 = v0 - mean, d1 = v1 - mean;
    float sq = d0 * d0 + d1 * d1;
    for (int off = 32; off; off >>= 1) sq += __shfl_down(sq, off, 64);
    if (lane == 0) red[4 + wid] = sq;
    __syncthreads();
    if (tid == 0) red[4] = red[4] + red[5] + red[6] + red[7];
    __syncthreads();
    float rs = rsqrtf(red[4] * (1.f / D) + 1e-5f);
    xn[tid] = d0 * rs * ng[tid] + nb[tid];
    xn[tid + 256] = d1 * rs * ng[tid + 256] + nb[tid + 256];
    __syncthreads();
    for (int o = tid; o < OUTLEN * NC; o += 256) {
        float acc = cb[o];
        const float* wp = cw + (long)o * D;
        for (int d = 0; d < D; d++) acc += xn[d] * wp[d];
        out[b * OUTLEN * NC + o] = acc;
    }
}

extern "C" void kernel_launch(void* const* d_in, const int* in_sizes, int n_in,
                              void* d_out, int out_size, void* d_ws, size_t ws_size,
                              hipStream_t stream) {
    const int* src = (const int*)d_in[0];
    const unsigned char* pad = (const unsigned char*)d_in[1];
    const float* emb = (const float*)d_in[2];
    const float* cls_token = (const float*)d_in[3];
    const float* qkv_w = (const float*)d_in[4];
    const float* qkv_b = (const float*)d_in[5];
    const float* out_w = (const float*)d_in[6];
    const float* out_b = (const float*)d_in[7];
    const float* rel_emb = (const float*)d_in[8];
    const float* ln1_g = (const float*)d_in[9];
    const float* ln1_b = (const float*)d_in[10];
    const float* w1 = (const float*)d_in[11];
    const float* b1 = (const float*)d_in[12];
    const float* w2 = (const float*)d_in[13];
    const float* b2 = (const float*)d_in[14];
    const float* ln2_g = (const float*)d_in[15];
    const float* ln2_b = (const float*)d_in[16];
    const float* norm_g = (const float*)d_in[17];
    const float* norm_b = (const float*)d_in[18];
    const float* cls_w = (const float*)d_in[19];
    const float* cls_b = (const float*)d_in[20];
    float* out = (float*)d_out;

    char* ws = (char*)d_ws;
    const size_t XB = (size_t)B * L * D * 4;       // 16.8 MB
    const size_t QB = (size_t)B * L * 3 * D * 4;   // 50.4 MB
    float* x   = (float*)(ws);
    float* qkv = (float*)(ws + XB);
    float* o   = (float*)(ws + XB + QB);
    float* h   = qkv; // reuse [qkv|o] region: exactly B*L*FF*4 bytes
    float* p   = (float*)(ws + XB + QB + XB);      // o_proj / ff buffer
    float* x2  = (float*)(ws + XB + QB + XB + XB);

    const int M = B * L;
    {
        long total = (long)B * L * D;
        embed_k<<<dim3((unsigned)((total + 255) / 256)), 256, 0, stream>>>(src, emb, cls_token, x);
    }
    for (int l = 0; l < NL; l++) {
        const float* qw = qkv_w + (size_t)l * 3 * D * D;
        const float* qb = qkv_b + (size_t)l * 3 * D;
        const float* ow = out_w + (size_t)l * D * D;
        const float* ob = out_b + (size_t)l * D;
        const float* re = rel_emb + (size_t)l * (2 * MAXD + 1) * H;
        const float* g1 = ln1_g + (size_t)l * D;
        const float* be1 = ln1_b + (size_t)l * D;
        const float* W1p = w1 + (size_t)l * FF * D;
        const float* B1p = b1 + (size_t)l * FF;
        const float* W2p = w2 + (size_t)l * D * FF;
        const float* B2p = b2 + (size_t)l * D;
        const float* g2 = ln2_g + (size_t)l * D;
        const float* be2 = ln2_b + (size_t)l * D;

        gemm_k<<<dim3(3 * D / BN, (M + BM - 1) / BM), 256, 0, stream>>>(x, qw, qb, qkv, M, 3 * D, D, 0);
        fattn_k<<<dim3((L + 63) / 64, H, B), 256, 0, stream>>>(qkv, re, pad, o);
        gemm_k<<<dim3(D / BN, (M + BM - 1) / BM), 256, 0, stream>>>(o, ow, ob, p, M, D, D, 0);
        add_ln_k<<<dim3(M), 256, 0, stream>>>(x, p, g1, be1, x2);
        gemm_k<<<dim3(FF / BN, (M + BM - 1) / BM), 256, 0, stream>>>(x2, W1p, B1p, h, M, FF, D, 1);
        gemm_k<<<dim3(D / BN, (M + BM - 1) / BM), 256, 0, stream>>>(h, W2p, B2p, p, M, D, FF, 0);
        add_ln_k<<<dim3(M), 256, 0, stream>>>(x2, p, g2, be2, x);
    }
    cls_k<<<dim3(B), 256, 0, stream>>>(x, norm_g, norm_b, cls_w, cls_b, out);
}

// Round 3
// 3471.390 us; speedup vs baseline: 9.2450x; 2.9318x over previous
//
#include <hip/hip_runtime.h>
#include <hip/hip_bf16.h>
#include <stdint.h>

#define B 8
#define S 1024
#define L 1025
#define D 512
#define H 8
#define HD 64
#define NL 6
#define FF 2048
#define MAXD 64
#define OUTLEN 8
#define NC 10

#define MP 8320   // 65 * 128, padded M

typedef __bf16 bf16;
typedef __bf16 bf16x8 __attribute__((ext_vector_type(8)));
typedef __bf16 bf16x4 __attribute__((ext_vector_type(4)));
typedef float f32x4 __attribute__((ext_vector_type(4)));

__device__ __forceinline__ void gld16(const void* g, void* l) {
    __builtin_amdgcn_global_load_lds(
        (const __attribute__((address_space(1))) unsigned int*)g,
        (__attribute__((address_space(3))) unsigned int*)l,
        16, 0, 0);
}

// ---------------- f32 -> bf16 conversion (vectorized) ----------------
__global__ __launch_bounds__(256) void cvt_k(const float* __restrict__ in,
                                             bf16* __restrict__ out, int n4)
{
    int i = blockIdx.x * 256 + threadIdx.x;
    if (i >= n4) return;
    float4 v = reinterpret_cast<const float4*>(in)[i];
    bf16x4 o;
    o[0] = (bf16)v.x; o[1] = (bf16)v.y; o[2] = (bf16)v.z; o[3] = (bf16)v.w;
    reinterpret_cast<bf16x4*>(out)[i] = o;
}

// ---------------- embedding ----------------
__global__ void embed_k(const int* __restrict__ src, const float* __restrict__ emb,
                        const float* __restrict__ cls, float* __restrict__ x,
                        bf16* __restrict__ xb)
{
    long i = (long)blockIdx.x * blockDim.x + threadIdx.x; // over B*L*D
    if (i >= (long)B * L * D) return;
    int d = (int)(i % D);
    long bl = i / D;
    int l = (int)(bl % L);
    int b = (int)(bl / L);
    float v = (l == 0) ? cls[d] : emb[(long)src[b * S + (l - 1)] * D + d];
    x[i] = v;
    xb[i] = (bf16)v;
}

// ---------------- MFMA bf16 GEMM: C[MP,N] = A[MP,K] @ W[N,K]^T + bias ----------
// 128x128 tile, BK=32, 4 waves (2x2), 4x4 fragments of 16x16x32 per wave.
template<int ACT, int OBF>
__global__ __launch_bounds__(256) void mgemm(const bf16* __restrict__ A,
                                             const bf16* __restrict__ W,
                                             const float* __restrict__ bias,
                                             float* __restrict__ Cf,
                                             bf16* __restrict__ Cb,
                                             int N, int K)
{
    __shared__ bf16 Asl[128 * 32];
    __shared__ bf16 Bsl[128 * 32];
    int tid = threadIdx.x;
    int m0 = blockIdx.y * 128;
    int n0 = blockIdx.x * 128;
    int lane = tid & 63;
    int w = tid >> 6, wr = w >> 1, wc = w & 1;
    int wbase = tid & ~63;
    int kb = (lane >> 4) * 8;
    int rsel = lane & 15;
    f32x4 acc[4][4] = {};

    for (int k0 = 0; k0 < K; k0 += 32) {
#pragma unroll
        for (int r = 0; r < 2; r++) {
            int s = r * 256 + tid;
            int sb = r * 256 + wbase;
            gld16(A + (size_t)(m0 + (s >> 2)) * K + k0 + (s & 3) * 8, &Asl[(size_t)sb * 8]);
            gld16(W + (size_t)(n0 + (s >> 2)) * K + k0 + (s & 3) * 8, &Bsl[(size_t)sb * 8]);
        }
        __syncthreads();
        bf16x8 af[4], bfr[4];
#pragma unroll
        for (int fi = 0; fi < 4; fi++)
            af[fi] = *reinterpret_cast<const bf16x8*>(&Asl[(wr * 64 + fi * 16 + rsel) * 32 + kb]);
#pragma unroll
        for (int fj = 0; fj < 4; fj++)
            bfr[fj] = *reinterpret_cast<const bf16x8*>(&Bsl[(wc * 64 + fj * 16 + rsel) * 32 + kb]);
#pragma unroll
        for (int fi = 0; fi < 4; fi++)
#pragma unroll
            for (int fj = 0; fj < 4; fj++)
                acc[fi][fj] = __builtin_amdgcn_mfma_f32_16x16x32_bf16(af[fi], bfr[fj], acc[fi][fj], 0, 0, 0);
        __syncthreads();
    }
    int rowb = (lane >> 4) * 4;
    int colb = lane & 15;
#pragma unroll
    for (int fi = 0; fi < 4; fi++) {
#pragma unroll
        for (int fj = 0; fj < 4; fj++) {
            int col = n0 + wc * 64 + fj * 16 + colb;
            float bsv = bias[col];
#pragma unroll
            for (int i = 0; i < 4; i++) {
                int row = m0 + wr * 64 + fi * 16 + rowb + i;
                float v = acc[fi][fj][i] + bsv;
                if (ACT) v = 0.5f * v * (1.f + erff(v * 0.70710678118654752f));
                if (OBF) Cb[(size_t)row * N + col] = (bf16)v;
                else     Cf[(size_t)row * N + col] = v;
            }
        }
    }
}

// ---------------- flash attention: one block per (64-row q-tile, h, b) --------
__global__ __launch_bounds__(256) void fattn_k(const float* __restrict__ qkv,
                                               const float* __restrict__ rel_emb_l,
                                               const unsigned char* __restrict__ pad,
                                               bf16* __restrict__ ob)
{
    int qt = blockIdx.x;
    int h = blockIdx.y;
    int b = blockIdx.z;
    int q0 = qt * 64;
    __shared__ float Qs[64][68];   // [d][r], pre-scaled
    __shared__ float Ks[64][68];   // [d][c]
    __shared__ float Vs[64][68];   // [k][d]
    __shared__ float Ps[64][68];   // [k][r]
    __shared__ float bias_s[2 * MAXD + 1];
    __shared__ unsigned char maskf[64];
    int tid = threadIdx.x;
    int tx = tid & 15, ty = tid >> 4;
    const float scale = 0.125f;
    const long bh_base = (long)(b * L) * (3 * D) + h * HD;

#pragma unroll
    for (int i = 0; i < 4; i++) {
        int idx = tid + i * 256;
        int r = idx >> 4, c4 = idx & 15;
        int gq = q0 + r;
        float4 v = make_float4(0.f, 0.f, 0.f, 0.f);
        if (gq < L) v = *reinterpret_cast<const float4*>(qkv + bh_base + (long)gq * (3 * D) + c4 * 4);
        Qs[c4 * 4 + 0][r] = v.x * scale;
        Qs[c4 * 4 + 1][r] = v.y * scale;
        Qs[c4 * 4 + 2][r] = v.z * scale;
        Qs[c4 * 4 + 3][r] = v.w * scale;
    }
    for (int rel = tid; rel < 2 * MAXD + 1; rel += 256) bias_s[rel] = rel_emb_l[rel * H + h];

    float Oacc[4][4] = {};
    float m_prev[4], l_sum[4];
#pragma unroll
    for (int i = 0; i < 4; i++) { m_prev[i] = -1e30f; l_sum[i] = 0.f; }

    const int NT = (L + 63) / 64; // 17
    for (int kt = 0; kt < NT; kt++) {
        int k0 = kt * 64;
        __syncthreads();
#pragma unroll
        for (int i = 0; i < 4; i++) {
            int idx = tid + i * 256;
            int r = idx >> 4, c4 = idx & 15;
            int gk = k0 + r;
            float4 kv = make_float4(0.f, 0.f, 0.f, 0.f);
            float4 vv = make_float4(0.f, 0.f, 0.f, 0.f);
            if (gk < L) {
                const float* rowp = qkv + bh_base + (long)gk * (3 * D);
                kv = *reinterpret_cast<const float4*>(rowp + D + c4 * 4);
                vv = *reinterpret_cast<const float4*>(rowp + 2 * D + c4 * 4);
            }
            Ks[c4 * 4 + 0][r] = kv.x;
            Ks[c4 * 4 + 1][r] = kv.y;
            Ks[c4 * 4 + 2][r] = kv.z;
            Ks[c4 * 4 + 3][r] = kv.w;
            *reinterpret_cast<float4*>(&Vs[r][c4 * 4]) = vv;
        }
        if (tid < 64) {
            int gk = k0 + tid;
            maskf[tid] = (gk >= L) || (gk > 0 && pad[b * S + gk - 1] != 0);
        }
        __syncthreads();

        float Sv[4][4] = {};
#pragma unroll
        for (int d = 0; d < 64; d++) {
            float4 a = *reinterpret_cast<const float4*>(&Qs[d][ty * 4]);
            float4 bb = *reinterpret_cast<const float4*>(&Ks[d][tx * 4]);
            float av[4] = {a.x, a.y, a.z, a.w};
            float bv[4] = {bb.x, bb.y, bb.z, bb.w};
#pragma unroll
            for (int i = 0; i < 4; i++)
#pragma unroll
                for (int j = 0; j < 4; j++)
                    Sv[i][j] += av[i] * bv[j];
        }
#pragma unroll
        for (int i = 0; i < 4; i++) {
            int rg = q0 + ty * 4 + i;
#pragma unroll
            for (int j = 0; j < 4; j++) {
                int cg = k0 + tx * 4 + j;
                int rel = cg - rg;
                rel = min(MAXD, max(-MAXD, rel)) + MAXD;
                Sv[i][j] += bias_s[rel];
                if (maskf[tx * 4 + j]) Sv[i][j] = -1e9f;
            }
        }
        float Pv[4][4];
#pragma unroll
        for (int i = 0; i < 4; i++) {
            float mx = fmaxf(fmaxf(Sv[i][0], Sv[i][1]), fmaxf(Sv[i][2], Sv[i][3]));
#pragma unroll
            for (int mskk = 1; mskk < 16; mskk <<= 1) mx = fmaxf(mx, __shfl_xor(mx, mskk, 16));
            float mnew = fmaxf(m_prev[i], mx);
            float corr = __expf(m_prev[i] - mnew);
            float ssum = 0.f;
#pragma unroll
            for (int j = 0; j < 4; j++) {
                float p = __expf(Sv[i][j] - mnew);
                Pv[i][j] = p;
                ssum += p;
            }
#pragma unroll
            for (int mskk = 1; mskk < 16; mskk <<= 1) ssum += __shfl_xor(ssum, mskk, 16);
            l_sum[i] = l_sum[i] * corr + ssum;
            m_prev[i] = mnew;
#pragma unroll
            for (int j = 0; j < 4; j++) Oacc[i][j] *= corr;
        }
#pragma unroll
        for (int i = 0; i < 4; i++)
#pragma unroll
            for (int j = 0; j < 4; j++)
                Ps[tx * 4 + j][ty * 4 + i] = Pv[i][j];
        __syncthreads();
#pragma unroll
        for (int k = 0; k < 64; k++) {
            float4 a = *reinterpret_cast<const float4*>(&Ps[k][ty * 4]);
            float4 bb = *reinterpret_cast<const float4*>(&Vs[k][tx * 4]);
            float av[4] = {a.x, a.y, a.z, a.w};
            float bv[4] = {bb.x, bb.y, bb.z, bb.w};
#pragma unroll
            for (int i = 0; i < 4; i++)
#pragma unroll
                for (int j = 0; j < 4; j++)
                    Oacc[i][j] += av[i] * bv[j];
        }
    }
#pragma unroll
    for (int i = 0; i < 4; i++) {
        int rg = q0 + ty * 4 + i;
        if (rg >= L) continue;
        float inv = 1.f / l_sum[i];
        bf16x4 r4;
        r4[0] = (bf16)(Oacc[i][0] * inv);
        r4[1] = (bf16)(Oacc[i][1] * inv);
        r4[2] = (bf16)(Oacc[i][2] * inv);
        r4[3] = (bf16)(Oacc[i][3] * inv);
        *reinterpret_cast<bf16x4*>(ob + (size_t)(b * L + rg) * D + h * HD + tx * 4) = r4;
    }
}

// ---------------- out = LayerNorm(xin + rin), f32 + bf16 copies ----------------
__global__ __launch_bounds__(256) void add_ln_k(const float* __restrict__ xin,
                                                const float* __restrict__ rin,
                                                const float* __restrict__ g,
                                                const float* __restrict__ bb,
                                                float* __restrict__ out,
                                                bf16* __restrict__ outb)
{
    int row = blockIdx.x;
    __shared__ float red[8];
    int tid = threadIdx.x;
    const float* xp = xin + (size_t)row * D;
    const float* rp = rin + (size_t)row * D;
    float v0 = xp[tid] + rp[tid];
    float v1 = xp[tid + 256] + rp[tid + 256];
    float s = v0 + v1;
    for (int off = 32; off; off >>= 1) s += __shfl_down(s, off, 64);
    int lane = tid & 63, wid = tid >> 6;
    if (lane == 0) red[wid] = s;
    __syncthreads();
    if (tid == 0) red[0] = red[0] + red[1] + red[2] + red[3];
    __syncthreads();
    float mean = red[0] * (1.f / D);
    float d0 = v0 - mean, d1 = v1 - mean;
    float sq = d0 * d0 + d1 * d1;
    for (int off = 32; off; off >>= 1) sq += __shfl_down(sq, off, 64);
    if (lane == 0) red[4 + wid] = sq;
    __syncthreads();
    if (tid == 0) red[4] = red[4] + red[5] + red[6] + red[7];
    __syncthreads();
    float rs = rsqrtf(red[4] * (1.f / D) + 1e-5f);
    float r0 = d0 * rs * g[tid] + bb[tid];
    float r1 = d1 * rs * g[tid + 256] + bb[tid + 256];
    out[(size_t)row * D + tid] = r0;
    out[(size_t)row * D + tid + 256] = r1;
    outb[(size_t)row * D + tid] = (bf16)r0;
    outb[(size_t)row * D + tid + 256] = (bf16)r1;
}

// ---------------- final LN (row 0 only) + classifier ----------------
__global__ __launch_bounds__(256) void cls_k(const float* __restrict__ x,
                                             const float* __restrict__ ng,
                                             const float* __restrict__ nb,
                                             const float* __restrict__ cw,
                                             const float* __restrict__ cb,
                                             float* __restrict__ out)
{
    int b = blockIdx.x;
    __shared__ float xn[D];
    __shared__ float red[8];
    int tid = threadIdx.x;
    const float* xp = x + (size_t)(b * L) * D;
    float v0 = xp[tid], v1 = xp[tid + 256];
    float s = v0 + v1;
    for (int off = 32; off; off >>= 1) s += __shfl_down(s, off, 64);
    int lane = tid & 63, wid = tid >> 6;
    if (lane == 0) red[wid] = s;
    __syncthreads();
    if (tid == 0) red[0] = red[0] + red[1] + red[2] + red[3];
    __syncthreads();
    float mean = red[0] * (1.f / D);
    float d0 = v0 - mean, d1 = v1 - mean;
    float sq = d0 * d0 + d1 * d1;
    for (int off = 32; off; off >>= 1) sq += __shfl_down(sq, off, 64);
    if (lane == 0) red[4 + wid] = sq;
    __syncthreads();
    if (tid == 0) red[4] = red[4] + red[5] + red[6] + red[7];
    __syncthreads();
    float rs = rsqrtf(red[4] * (1.f / D) + 1e-5f);
    xn[tid] = d0 * rs * ng[tid] + nb[tid];
    xn[tid + 256] = d1 * rs * ng[tid + 256] + nb[tid + 256];
    __syncthreads();
    for (int o = tid; o < OUTLEN * NC; o += 256) {
        float acc = cb[o];
        const float* wp = cw + (size_t)o * D;
        for (int d = 0; d < D; d++) acc += xn[d] * wp[d];
        out[b * OUTLEN * NC + o] = acc;
    }
}

extern "C" void kernel_launch(void* const* d_in, const int* in_sizes, int n_in,
                              void* d_out, int out_size, void* d_ws, size_t ws_size,
                              hipStream_t stream) {
    const int* src = (const int*)d_in[0];
    const unsigned char* pad = (const unsigned char*)d_in[1];
    const float* emb = (const float*)d_in[2];
    const float* cls_token = (const float*)d_in[3];
    const float* qkv_w = (const float*)d_in[4];
    const float* qkv_b = (const float*)d_in[5];
    const float* out_w = (const float*)d_in[6];
    const float* out_b = (const float*)d_in[7];
    const float* rel_emb = (const float*)d_in[8];
    const float* ln1_g = (const float*)d_in[9];
    const float* ln1_b = (const float*)d_in[10];
    const float* w1 = (const float*)d_in[11];
    const float* b1 = (const float*)d_in[12];
    const float* w2 = (const float*)d_in[13];
    const float* b2 = (const float*)d_in[14];
    const float* ln2_g = (const float*)d_in[15];
    const float* ln2_b = (const float*)d_in[16];
    const float* norm_g = (const float*)d_in[17];
    const float* norm_b = (const float*)d_in[18];
    const float* cls_w = (const float*)d_in[19];
    const float* cls_b = (const float*)d_in[20];
    float* out = (float*)d_out;

    char* ws = (char*)d_ws;
    size_t off = 0;
    float* x   = (float*)(ws + off); off += (size_t)MP * D * 4;
    bf16*  xb  = (bf16*) (ws + off); off += (size_t)MP * D * 2;
    float* x2  = (float*)(ws + off); off += (size_t)MP * D * 4;
    bf16*  x2b = (bf16*) (ws + off); off += (size_t)MP * D * 2;
    char*  R   = ws + off;           off += (size_t)MP * 3 * D * 4; // qkv | (hb + p)
    float* qkv = (float*)R;
    bf16*  hb  = (bf16*)R;                               // MP*FF*2 = 34,078,720
    float* p   = (float*)(R + (size_t)MP * FF * 2);      // MP*D*4  = 17,039,360
    bf16*  obf = (bf16*) (ws + off); off += (size_t)MP * D * 2;

    const size_t WQ = (size_t)NL * 3 * D * D;   // 2,359,296 elems
    const size_t WO = (size_t)NL * D * D;       //   1,572,864? no: 6*512*512=1,572,864
    const size_t W1E = (size_t)NL * FF * D;
    const size_t W2E = (size_t)NL * D * FF;
    const size_t WALL = WQ + WO + W1E + W2E;
    bool all_w = (off + WALL * 2) <= ws_size;

    bf16 *wq_a = nullptr, *wo_a = nullptr, *w1_a = nullptr, *w2_a = nullptr, *wbuf = nullptr;
    if (all_w) {
        wq_a = (bf16*)(ws + off);
        wo_a = wq_a + WQ;
        w1_a = wo_a + WO;
        w2_a = w1_a + W1E;
        int n4;
        n4 = (int)(WQ / 4);  cvt_k<<<dim3((n4 + 255) / 256), 256, 0, stream>>>(qkv_w, wq_a, n4);
        n4 = (int)(WO / 4);  cvt_k<<<dim3((n4 + 255) / 256), 256, 0, stream>>>(out_w, wo_a, n4);
        n4 = (int)(W1E / 4); cvt_k<<<dim3((n4 + 255) / 256), 256, 0, stream>>>(w1, w1_a, n4);
        n4 = (int)(W2E / 4); cvt_k<<<dim3((n4 + 255) / 256), 256, 0, stream>>>(w2, w2_a, n4);
    } else {
        wbuf = (bf16*)(ws + off); // per-layer rotating buffer
    }

    const int M = B * L;
    {
        long total = (long)B * L * D;
        embed_k<<<dim3((unsigned)((total + 255) / 256)), 256, 0, stream>>>(src, emb, cls_token, x, xb);
    }
    for (int l = 0; l < NL; l++) {
        const float* qb  = qkv_b + (size_t)l * 3 * D;
        const float* obi = out_b + (size_t)l * D;
        const float* re  = rel_emb + (size_t)l * (2 * MAXD + 1) * H;
        const float* g1  = ln1_g + (size_t)l * D;
        const float* be1 = ln1_b + (size_t)l * D;
        const float* B1p = b1 + (size_t)l * FF;
        const float* B2p = b2 + (size_t)l * D;
        const float* g2  = ln2_g + (size_t)l * D;
        const float* be2 = ln2_b + (size_t)l * D;

        const bf16 *wqb, *wob, *w1b, *w2b;
        if (all_w) {
            wqb = wq_a + (size_t)l * 3 * D * D;
            wob = wo_a + (size_t)l * D * D;
            w1b = w1_a + (size_t)l * FF * D;
            w2b = w2_a + (size_t)l * D * FF;
        } else {
            bf16* wp_ = wbuf;
            wqb = wp_;            wp_ += 3 * D * D;
            wob = wp_;            wp_ += D * D;
            w1b = wp_;            wp_ += FF * D;
            w2b = wp_;
            int n4;
            n4 = 3 * D * D / 4; cvt_k<<<dim3((n4 + 255) / 256), 256, 0, stream>>>(qkv_w + (size_t)l * 3 * D * D, (bf16*)wqb, n4);
            n4 = D * D / 4;     cvt_k<<<dim3((n4 + 255) / 256), 256, 0, stream>>>(out_w + (size_t)l * D * D, (bf16*)wob, n4);
            n4 = FF * D / 4;    cvt_k<<<dim3((n4 + 255) / 256), 256, 0, stream>>>(w1 + (size_t)l * FF * D, (bf16*)w1b, n4);
            n4 = D * FF / 4;    cvt_k<<<dim3((n4 + 255) / 256), 256, 0, stream>>>(w2 + (size_t)l * D * FF, (bf16*)w2b, n4);
        }

        mgemm<0, 0><<<dim3(3 * D / 128, MP / 128), 256, 0, stream>>>(xb, wqb, qb, qkv, nullptr, 3 * D, D);
        fattn_k<<<dim3((L + 63) / 64, H, B), 256, 0, stream>>>(qkv, re, pad, obf);
        mgemm<0, 0><<<dim3(D / 128, MP / 128), 256, 0, stream>>>(obf, wob, obi, p, nullptr, D, D);
        add_ln_k<<<dim3(M), 256, 0, stream>>>(x, p, g1, be1, x2, x2b);
        mgemm<1, 1><<<dim3(FF / 128, MP / 128), 256, 0, stream>>>(x2b, w1b, B1p, nullptr, hb, FF, D);
        mgemm<0, 0><<<dim3(D / 128, MP / 128), 256, 0, stream>>>(hb, w2b, B2p, p, nullptr, D, FF);
        add_ln_k<<<dim3(M), 256, 0, stream>>>(x2, p, g2, be2, x, xb);
    }
    cls_k<<<dim3(B), 256, 0, stream>>>(x, norm_g, norm_b, cls_w, cls_b, out);
}

// Round 4
// 1588.669 us; speedup vs baseline: 20.2012x; 2.1851x over previous
//
#include <hip/hip_runtime.h>
#include <hip/hip_bf16.h>
#include <stdint.h>

#define B 8
#define S 1024
#define L 1025
#define D 512
#define H 8
#define HD 64
#define NL 6
#define FF 2048
#define MAXD 64
#define OUTLEN 8
#define NC 10

#define MP 8320   // 65 * 128, padded M

typedef __bf16 bf16;
typedef __bf16 bf16x8 __attribute__((ext_vector_type(8)));
typedef __bf16 bf16x4 __attribute__((ext_vector_type(4)));
typedef float f32x4 __attribute__((ext_vector_type(4)));

__device__ __forceinline__ void gld16(const void* g, void* l) {
    __builtin_amdgcn_global_load_lds(
        (const __attribute__((address_space(1))) unsigned int*)g,
        (__attribute__((address_space(3))) unsigned int*)l,
        16, 0, 0);
}

// ---------------- f32 -> bf16 conversion (vectorized) ----------------
__global__ __launch_bounds__(256) void cvt_k(const float* __restrict__ in,
                                             bf16* __restrict__ out, int n4)
{
    int i = blockIdx.x * 256 + threadIdx.x;
    if (i >= n4) return;
    float4 v = reinterpret_cast<const float4*>(in)[i];
    bf16x4 o;
    o[0] = (bf16)v.x; o[1] = (bf16)v.y; o[2] = (bf16)v.z; o[3] = (bf16)v.w;
    reinterpret_cast<bf16x4*>(out)[i] = o;
}

// ---------------- embedding ----------------
__global__ void embed_k(const int* __restrict__ src, const float* __restrict__ emb,
                        const float* __restrict__ cls, float* __restrict__ x,
                        bf16* __restrict__ xb)
{
    long i = (long)blockIdx.x * blockDim.x + threadIdx.x; // over B*L*D
    if (i >= (long)B * L * D) return;
    int d = (int)(i % D);
    long bl = i / D;
    int l = (int)(bl % L);
    int b = (int)(bl / L);
    float v = (l == 0) ? cls[d] : emb[(long)src[b * S + (l - 1)] * D + d];
    x[i] = v;
    xb[i] = (bf16)v;
}

// ---------------- MFMA bf16 GEMM: C[MP,N] = A[MP,K] @ W[N,K]^T + bias ----------
// 128x128 tile, BK=32, 4 waves (2x2), 4x4 fragments of 16x16x32 per wave.
template<int ACT, int OBF>
__global__ __launch_bounds__(256) void mgemm(const bf16* __restrict__ A,
                                             const bf16* __restrict__ W,
                                             const float* __restrict__ bias,
                                             float* __restrict__ Cf,
                                             bf16* __restrict__ Cb,
                                             int N, int K)
{
    __shared__ bf16 Asl[128 * 32];
    __shared__ bf16 Bsl[128 * 32];
    int tid = threadIdx.x;
    int m0 = blockIdx.y * 128;
    int n0 = blockIdx.x * 128;
    int lane = tid & 63;
    int w = tid >> 6, wr = w >> 1, wc = w & 1;
    int wbase = tid & ~63;
    int kb = (lane >> 4) * 8;
    int rsel = lane & 15;
    f32x4 acc[4][4] = {};

    for (int k0 = 0; k0 < K; k0 += 32) {
#pragma unroll
        for (int r = 0; r < 2; r++) {
            int s = r * 256 + tid;
            int sb = r * 256 + wbase;
            gld16(A + (size_t)(m0 + (s >> 2)) * K + k0 + (s & 3) * 8, &Asl[(size_t)sb * 8]);
            gld16(W + (size_t)(n0 + (s >> 2)) * K + k0 + (s & 3) * 8, &Bsl[(size_t)sb * 8]);
        }
        __syncthreads();
        bf16x8 af[4], bfr[4];
#pragma unroll
        for (int fi = 0; fi < 4; fi++)
            af[fi] = *reinterpret_cast<const bf16x8*>(&Asl[(wr * 64 + fi * 16 + rsel) * 32 + kb]);
#pragma unroll
        for (int fj = 0; fj < 4; fj++)
            bfr[fj] = *reinterpret_cast<const bf16x8*>(&Bsl[(wc * 64 + fj * 16 + rsel) * 32 + kb]);
#pragma unroll
        for (int fi = 0; fi < 4; fi++)
#pragma unroll
            for (int fj = 0; fj < 4; fj++)
                acc[fi][fj] = __builtin_amdgcn_mfma_f32_16x16x32_bf16(af[fi], bfr[fj], acc[fi][fj], 0, 0, 0);
        __syncthreads();
    }
    int rowb = (lane >> 4) * 4;
    int colb = lane & 15;
#pragma unroll
    for (int fi = 0; fi < 4; fi++) {
#pragma unroll
        for (int fj = 0; fj < 4; fj++) {
            int col = n0 + wc * 64 + fj * 16 + colb;
            float bsv = bias[col];
#pragma unroll
            for (int i = 0; i < 4; i++) {
                int row = m0 + wr * 64 + fi * 16 + rowb + i;
                float v = acc[fi][fj][i] + bsv;
                if (ACT) v = 0.5f * v * (1.f + erff(v * 0.70710678118654752f));
                if (OBF) Cb[(size_t)row * N + col] = (bf16)v;
                else     Cf[(size_t)row * N + col] = v;
            }
        }
    }
}

// ---------------- MFMA flash attention: block = (64-row q-tile, h, b) ----------
// 4 waves, wave w owns q-rows w*16..w*16+15. KVBLK=64, 17 tiles.
__global__ __launch_bounds__(256) void fattn_k(const bf16* __restrict__ qkv,
                                               const float* __restrict__ rel_emb_l,
                                               const unsigned char* __restrict__ pad,
                                               bf16* __restrict__ ob)
{
    constexpr int PIT = 72; // bf16 pitch: 144 B rows -> 16B-aligned, 2-way-max frag reads
    int qt = blockIdx.x, h = blockIdx.y, b = blockIdx.z;
    int q0 = qt * 64;
    __shared__ bf16 Qs[64 * PIT];   // Q[q][d]; reused as Ps[r][c] after frag hoist
    __shared__ bf16 Ks[64 * PIT];   // K[k][d] natural
    __shared__ bf16 Vt[64 * PIT];   // V^T[d][k], XOR-swizzled k
    __shared__ float bias_s[2 * MAXD + 1];
    __shared__ float msk_s[64];
    bf16* Ps = Qs;
    int tid = threadIdx.x;
    int lane = tid & 63;
    int w = tid >> 6;
    int ln15 = lane & 15;
    int g4 = lane >> 4;   // 0..3
    int kb8 = g4 * 8;
    const size_t bbase = (size_t)b * L * (3 * D) + (size_t)h * HD;

    // stage Q (rows beyond L read valid-but-garbage memory; outputs discarded)
#pragma unroll
    for (int it = 0; it < 2; it++) {
        int s = tid + it * 256;
        int r = s >> 3, d0 = (s & 7) * 8;
        *(bf16x8*)(&Qs[r * PIT + d0]) =
            *(const bf16x8*)(qkv + bbase + (size_t)(q0 + r) * (3 * D) + d0);
    }
    for (int i = tid; i < 2 * MAXD + 1; i += 256) bias_s[i] = rel_emb_l[i * H + h];
    __syncthreads();

    // hoist Q A-fragments to registers (frees Qs for Ps)
    bf16x8 qa0 = *(const bf16x8*)(&Qs[(w * 16 + ln15) * PIT + kb8]);
    bf16x8 qa1 = *(const bf16x8*)(&Qs[(w * 16 + ln15) * PIT + 32 + kb8]);

    f32x4 oacc[4] = {};
    float m_prev[4], l_sum[4];
#pragma unroll
    for (int i = 0; i < 4; i++) { m_prev[i] = -1e30f; l_sum[i] = 0.f; }

    for (int kt = 0; kt < 17; kt++) {
        int k0 = kt * 64;
        __syncthreads(); // prev tile's Ks/Vt/Ps readers done (also covers Q-frag hoist)
#pragma unroll
        for (int it = 0; it < 2; it++) {
            int s = tid + it * 256;
            int r = s >> 3, d0 = (s & 7) * 8;
            const bf16* rp = qkv + bbase + (size_t)(k0 + r) * (3 * D);
            bf16x8 kv = *(const bf16x8*)(rp + D + d0);
            bf16x8 vv = *(const bf16x8*)(rp + 2 * D + d0);
            *(bf16x8*)(&Ks[r * PIT + d0]) = kv;
            int ksw = r ^ ((s & 7) << 3); // swizzle: spreads d0-groups across banks
#pragma unroll
            for (int j = 0; j < 8; j++)
                Vt[(d0 + j) * PIT + ksw] = vv[j];
        }
        if (tid < 64) {
            int gk = k0 + tid;
            msk_s[tid] = (gk >= L || (gk > 0 && pad[(size_t)b * S + gk - 1])) ? -1e9f : 0.f;
        }
        __syncthreads();

        // S = Q @ K^T : 8 MFMA
        f32x4 sacc[4] = {};
#pragma unroll
        for (int fj = 0; fj < 4; fj++) {
            bf16x8 kf0 = *(const bf16x8*)(&Ks[(fj * 16 + ln15) * PIT + kb8]);
            bf16x8 kf1 = *(const bf16x8*)(&Ks[(fj * 16 + ln15) * PIT + 32 + kb8]);
            sacc[fj] = __builtin_amdgcn_mfma_f32_16x16x32_bf16(qa0, kf0, sacc[fj], 0, 0, 0);
            sacc[fj] = __builtin_amdgcn_mfma_f32_16x16x32_bf16(qa1, kf1, sacc[fj], 0, 0, 0);
        }
        // scale + rel-bias + mask (C-frag: row=g4*4+i, col=fj*16+ln15)
        int rbase = q0 + w * 16 + g4 * 4;
        float sv[4][4];
#pragma unroll
        for (int fj = 0; fj < 4; fj++) {
            int cg = k0 + fj * 16 + ln15;
            float mv = msk_s[fj * 16 + ln15];
#pragma unroll
            for (int i = 0; i < 4; i++) {
                int rel = cg - (rbase + i);
                rel = min(MAXD, max(-MAXD, rel)) + MAXD;
                sv[fj][i] = sacc[fj][i] * 0.125f + bias_s[rel] + mv;
            }
        }
        // online softmax per row i (state replicated over the 16-lane col group)
        float pb[4][4];
#pragma unroll
        for (int i = 0; i < 4; i++) {
            float mx = fmaxf(fmaxf(sv[0][i], sv[1][i]), fmaxf(sv[2][i], sv[3][i]));
#pragma unroll
            for (int msk = 1; msk < 16; msk <<= 1) mx = fmaxf(mx, __shfl_xor(mx, msk, 16));
            float mnew = fmaxf(m_prev[i], mx);
            float corr = __expf(m_prev[i] - mnew);
            float sum = 0.f;
#pragma unroll
            for (int fj = 0; fj < 4; fj++) {
                float p = __expf(sv[fj][i] - mnew);
                pb[fj][i] = p;
                sum += p;
            }
#pragma unroll
            for (int msk = 1; msk < 16; msk <<= 1) sum += __shfl_xor(sum, msk, 16);
            l_sum[i] = l_sum[i] * corr + sum;
            m_prev[i] = mnew;
#pragma unroll
            for (int fd = 0; fd < 4; fd++) oacc[fd][i] *= corr;
        }
        // P -> LDS bf16 (row-XOR swizzled)
#pragma unroll
        for (int i = 0; i < 4; i++) {
            int r = w * 16 + g4 * 4 + i;
            int cx = ((r >> 2) & 7) << 3;
#pragma unroll
            for (int fj = 0; fj < 4; fj++)
                Ps[r * PIT + ((fj * 16 + ln15) ^ cx)] = (bf16)pb[fj][i];
        }
        __syncthreads();
        // O += P @ V : 8 MFMA (A-frag from Ps, B-frag from swizzled Vt)
        int arow = w * 16 + ln15;
        int ax = ((arow >> 2) & 7) << 3;
        bf16x8 pa0 = *(const bf16x8*)(&Ps[arow * PIT + (kb8 ^ ax)]);
        bf16x8 pa1 = *(const bf16x8*)(&Ps[arow * PIT + ((32 + kb8) ^ ax)]);
#pragma unroll
        for (int fd = 0; fd < 4; fd++) {
            int d = fd * 16 + ln15;
            int vx = ((d >> 3) & 7) << 3;
            bf16x8 vf0 = *(const bf16x8*)(&Vt[d * PIT + (kb8 ^ vx)]);
            bf16x8 vf1 = *(const bf16x8*)(&Vt[d * PIT + ((32 + kb8) ^ vx)]);
            oacc[fd] = __builtin_amdgcn_mfma_f32_16x16x32_bf16(pa0, vf0, oacc[fd], 0, 0, 0);
            oacc[fd] = __builtin_amdgcn_mfma_f32_16x16x32_bf16(pa1, vf1, oacc[fd], 0, 0, 0);
        }
    }
    // epilogue
#pragma unroll
    for (int i = 0; i < 4; i++) {
        int rg = q0 + w * 16 + g4 * 4 + i;
        if (rg >= L) continue;
        float inv = 1.f / l_sum[i];
#pragma unroll
        for (int fd = 0; fd < 4; fd++)
            ob[(size_t)(b * L + rg) * D + h * HD + fd * 16 + ln15] = (bf16)(oacc[fd][i] * inv);
    }
}

// ---------------- out = LayerNorm(xin + rin), f32 + bf16 copies ----------------
__global__ __launch_bounds__(256) void add_ln_k(const float* __restrict__ xin,
                                                const float* __restrict__ rin,
                                                const float* __restrict__ g,
                                                const float* __restrict__ bb,
                                                float* __restrict__ out,
                                                bf16* __restrict__ outb)
{
    int row = blockIdx.x;
    __shared__ float red[8];
    int tid = threadIdx.x;
    const float* xp = xin + (size_t)row * D;
    const float* rp = rin + (size_t)row * D;
    float v0 = xp[tid] + rp[tid];
    float v1 = xp[tid + 256] + rp[tid + 256];
    float s = v0 + v1;
    for (int off = 32; off; off >>= 1) s += __shfl_down(s, off, 64);
    int lane = tid & 63, wid = tid >> 6;
    if (lane == 0) red[wid] = s;
    __syncthreads();
    if (tid == 0) red[0] = red[0] + red[1] + red[2] + red[3];
    __syncthreads();
    float mean = red[0] * (1.f / D);
    float d0 = v0 - mean, d1 = v1 - mean;
    float sq = d0 * d0 + d1 * d1;
    for (int off = 32; off; off >>= 1) sq += __shfl_down(sq, off, 64);
    if (lane == 0) red[4 + wid] = sq;
    __syncthreads();
    if (tid == 0) red[4] = red[4] + red[5] + red[6] + red[7];
    __syncthreads();
    float rs = rsqrtf(red[4] * (1.f / D) + 1e-5f);
    float r0 = d0 * rs * g[tid] + bb[tid];
    float r1 = d1 * rs * g[tid + 256] + bb[tid + 256];
    out[(size_t)row * D + tid] = r0;
    out[(size_t)row * D + tid + 256] = r1;
    outb[(size_t)row * D + tid] = (bf16)r0;
    outb[(size_t)row * D + tid + 256] = (bf16)r1;
}

// ---------------- final LN (row 0 only) + classifier ----------------
__global__ __launch_bounds__(256) void cls_k(const float* __restrict__ x,
                                             const float* __restrict__ ng,
                                             const float* __restrict__ nb,
                                             const float* __restrict__ cw,
                                             const float* __restrict__ cb,
                                             float* __restrict__ out)
{
    int b = blockIdx.x;
    __shared__ float xn[D];
    __shared__ float red[8];
    int tid = threadIdx.x;
    const float* xp = x + (size_t)(b * L) * D;
    float v0 = xp[tid], v1 = xp[tid + 256];
    float s = v0 + v1;
    for (int off = 32; off; off >>= 1) s += __shfl_down(s, off, 64);
    int lane = tid & 63, wid = tid >> 6;
    if (lane == 0) red[wid] = s;
    __syncthreads();
    if (tid == 0) red[0] = red[0] + red[1] + red[2] + red[3];
    __syncthreads();
    float mean = red[0] * (1.f / D);
    float d0 = v0 - mean, d1 = v1 - mean;
    float sq = d0 * d0 + d1 * d1;
    for (int off = 32; off; off >>= 1) sq += __shfl_down(sq, off, 64);
    if (lane == 0) red[4 + wid] = sq;
    __syncthreads();
    if (tid == 0) red[4] = red[4] + red[5] + red[6] + red[7];
    __syncthreads();
    float rs = rsqrtf(red[4] * (1.f / D) + 1e-5f);
    xn[tid] = d0 * rs * ng[tid] + nb[tid];
    xn[tid + 256] = d1 * rs * ng[tid + 256] + nb[tid + 256];
    __syncthreads();
    for (int o = tid; o < OUTLEN * NC; o += 256) {
        float acc = cb[o];
        const float* wp = cw + (size_t)o * D;
        for (int d = 0; d < D; d++) acc += xn[d] * wp[d];
        out[b * OUTLEN * NC + o] = acc;
    }
}

extern "C" void kernel_launch(void* const* d_in, const int* in_sizes, int n_in,
                              void* d_out, int out_size, void* d_ws, size_t ws_size,
                              hipStream_t stream) {
    const int* src = (const int*)d_in[0];
    const unsigned char* pad = (const unsigned char*)d_in[1];
    const float* emb = (const float*)d_in[2];
    const float* cls_token = (const float*)d_in[3];
    const float* qkv_w = (const float*)d_in[4];
    const float* qkv_b = (const float*)d_in[5];
    const float* out_w = (const float*)d_in[6];
    const float* out_b = (const float*)d_in[7];
    const float* rel_emb = (const float*)d_in[8];
    const float* ln1_g = (const float*)d_in[9];
    const float* ln1_b = (const float*)d_in[10];
    const float* w1 = (const float*)d_in[11];
    const float* b1 = (const float*)d_in[12];
    const float* w2 = (const float*)d_in[13];
    const float* b2 = (const float*)d_in[14];
    const float* ln2_g = (const float*)d_in[15];
    const float* ln2_b = (const float*)d_in[16];
    const float* norm_g = (const float*)d_in[17];
    const float* norm_b = (const float*)d_in[18];
    const float* cls_w = (const float*)d_in[19];
    const float* cls_b = (const float*)d_in[20];
    float* out = (float*)d_out;

    char* ws = (char*)d_ws;
    size_t off = 0;
    float* x   = (float*)(ws + off); off += (size_t)MP * D * 4;
    bf16*  xb  = (bf16*) (ws + off); off += (size_t)MP * D * 2;
    float* x2  = (float*)(ws + off); off += (size_t)MP * D * 4;
    bf16*  x2b = (bf16*) (ws + off); off += (size_t)MP * D * 2;
    char*  R   = ws + off;           off += (size_t)MP * 3 * D * 4; // qkvb | (hb + p)
    bf16*  qkvb = (bf16*)R;                              // MP*3D*2 = 25.6 MB
    bf16*  hb  = (bf16*)R;                               // MP*FF*2 = 34.1 MB (after attn)
    float* p   = (float*)(R + (size_t)MP * FF * 2);      // MP*D*4  = 17.0 MB (disjoint from qkvb)
    bf16*  obf = (bf16*) (ws + off); off += (size_t)MP * D * 2;

    const size_t WQ = (size_t)NL * 3 * D * D;
    const size_t WO = (size_t)NL * D * D;
    const size_t W1E = (size_t)NL * FF * D;
    const size_t W2E = (size_t)NL * D * FF;
    const size_t WALL = WQ + WO + W1E + W2E;
    bool all_w = (off + WALL * 2) <= ws_size;

    bf16 *wq_a = nullptr, *wo_a = nullptr, *w1_a = nullptr, *w2_a = nullptr, *wbuf = nullptr;
    if (all_w) {
        wq_a = (bf16*)(ws + off);
        wo_a = wq_a + WQ;
        w1_a = wo_a + WO;
        w2_a = w1_a + W1E;
        int n4;
        n4 = (int)(WQ / 4);  cvt_k<<<dim3((n4 + 255) / 256), 256, 0, stream>>>(qkv_w, wq_a, n4);
        n4 = (int)(WO / 4);  cvt_k<<<dim3((n4 + 255) / 256), 256, 0, stream>>>(out_w, wo_a, n4);
        n4 = (int)(W1E / 4); cvt_k<<<dim3((n4 + 255) / 256), 256, 0, stream>>>(w1, w1_a, n4);
        n4 = (int)(W2E / 4); cvt_k<<<dim3((n4 + 255) / 256), 256, 0, stream>>>(w2, w2_a, n4);
    } else {
        wbuf = (bf16*)(ws + off); // per-layer rotating buffer
    }

    const int M = B * L;
    {
        long total = (long)B * L * D;
        embed_k<<<dim3((unsigned)((total + 255) / 256)), 256, 0, stream>>>(src, emb, cls_token, x, xb);
    }
    for (int l = 0; l < NL; l++) {
        const float* qb  = qkv_b + (size_t)l * 3 * D;
        const float* obi = out_b + (size_t)l * D;
        const float* re  = rel_emb + (size_t)l * (2 * MAXD + 1) * H;
        const float* g1  = ln1_g + (size_t)l * D;
        const float* be1 = ln1_b + (size_t)l * D;
        const float* B1p = b1 + (size_t)l * FF;
        const float* B2p = b2 + (size_t)l * D;
        const float* g2  = ln2_g + (size_t)l * D;
        const float* be2 = ln2_b + (size_t)l * D;

        const bf16 *wqb, *wob, *w1b, *w2b;
        if (all_w) {
            wqb = wq_a + (size_t)l * 3 * D * D;
            wob = wo_a + (size_t)l * D * D;
            w1b = w1_a + (size_t)l * FF * D;
            w2b = w2_a + (size_t)l * D * FF;
        } else {
            bf16* wp_ = wbuf;
            wqb = wp_;            wp_ += 3 * D * D;
            wob = wp_;            wp_ += D * D;
            w1b = wp_;            wp_ += FF * D;
            w2b = wp_;
            int n4;
            n4 = 3 * D * D / 4; cvt_k<<<dim3((n4 + 255) / 256), 256, 0, stream>>>(qkv_w + (size_t)l * 3 * D * D, (bf16*)wqb, n4);
            n4 = D * D / 4;     cvt_k<<<dim3((n4 + 255) / 256), 256, 0, stream>>>(out_w + (size_t)l * D * D, (bf16*)wob, n4);
            n4 = FF * D / 4;    cvt_k<<<dim3((n4 + 255) / 256), 256, 0, stream>>>(w1 + (size_t)l * FF * D, (bf16*)w1b, n4);
            n4 = D * FF / 4;    cvt_k<<<dim3((n4 + 255) / 256), 256, 0, stream>>>(w2 + (size_t)l * D * FF, (bf16*)w2b, n4);
        }

        mgemm<0, 1><<<dim3(3 * D / 128, MP / 128), 256, 0, stream>>>(xb, wqb, qb, nullptr, qkvb, 3 * D, D);
        fattn_k<<<dim3((L + 63) / 64, H, B), 256, 0, stream>>>(qkvb, re, pad, obf);
        mgemm<0, 0><<<dim3(D / 128, MP / 128), 256, 0, stream>>>(obf, wob, obi, p, nullptr, D, D);
        add_ln_k<<<dim3(M), 256, 0, stream>>>(x, p, g1, be1, x2, x2b);
        mgemm<1, 1><<<dim3(FF / 128, MP / 128), 256, 0, stream>>>(x2b, w1b, B1p, nullptr, hb, FF, D);
        mgemm<0, 0><<<dim3(D / 128, MP / 128), 256, 0, stream>>>(hb, w2b, B2p, p, nullptr, D, FF);
        add_ln_k<<<dim3(M), 256, 0, stream>>>(x2, p, g2, be2, x, xb);
    }
    cls_k<<<dim3(B), 256, 0, stream>>>(x, norm_g, norm_b, cls_w, cls_b, out);
}